// Round 1
// baseline (2469.054 us; speedup 1.0000x reference)
//
#include <hip/hip_runtime.h>

#define BB 256
#define TT 2048
#define SS 32
#define NN 19
#define NCLASS 10
#define NUNFOLD 6
#define EPSV 1e-8f
#define LOG2E 1.4426950408889634f
#define CH 128                 // timesteps per producer chunk
#define NCH (TT / CH)          // 16 chunks
#define SROW 39                // sens row: 19 num + 19 den + 1 pad (bank-spread)
#define NU 7                   // uniform pre-neuron loop: ceil(19/3) steps

// ---------------------------------------------------------------------------
template <int CTRL>
__device__ __forceinline__ float dpp_shl(float x)
{
    return __int_as_float(__builtin_amdgcn_update_dpp(
        0, __float_as_int(x), CTRL, 0xf, 0xf, true));
}

// VALU-pipe broadcast: v from a fixed lane into a wave-uniform (SGPR) value.
__device__ __forceinline__ float rdlane(float v, int l)
{
    return __int_as_float(__builtin_amdgcn_readlane(__float_as_int(v), l));
}

// ---------------------------------------------------------------------------
// Fused producer/consumer loop.  Wave 0 = scan chain, waves 1-3 = sensory
// producers (unchanged).  Scan redesign: the ds_bpermute gather (~150-210 cyc
// LDS round-trip inside the 336-cyc serial unfold) is replaced by a
// readlane->SGPR broadcast of all 19 v's + a uniform pre-neuron loop
// (i = 3u+h), keeping the whole unfold on the VALU pipe.  Per-lane source
// selection is folded into 3 FMAs per step via zeroed coefficients.
// ---------------------------------------------------------------------------
__device__ __forceinline__ void fused_loop(
    int tid, int lane, int wid, int b, int jc,
    const float (&cA)[NU], const float (&cB)[NU], const float (&cC)[NU],
    const float (&sb2)[NU], const float (&Aa)[NU], const float (&Wm)[NU],
    float cmt, float glvl, float cgl, float ow0, float ob0,
    const float* __restrict__ x,
    const float4* __restrict__ pq,   // LDS: folded sensory params [j*SS+s]
    float* __restrict__ sbuf,        // LDS: [2][CH][SROW]
    float* __restrict__ obuf)        // LDS: [TT] motor outputs
{
    float v = 0.f;
    float vS[NN];                    // wave-uniform copies of all neuron v's
#pragma unroll
    for (int i0 = 0; i0 < NN; i0++) vS[i0] = 0.f;

    for (int c = 0; c <= NCH; c++) {
        if (wid != 0) {
            if (c < NCH) {               // produce chunk c
                float* sb = sbuf + (c & 1) * (CH * SROW);
                const float* xb = x + ((long)b * TT + (long)c * CH) * SS;
                for (int tl = tid - 64; tl < CH; tl += 192) {
                    const float4* xr4 = (const float4*)(xb + tl * SS);
                    float xs[SS];
#pragma unroll
                    for (int q = 0; q < SS / 4; q++) {
                        float4 v4 = xr4[q];
                        xs[4 * q + 0] = v4.x; xs[4 * q + 1] = v4.y;
                        xs[4 * q + 2] = v4.z; xs[4 * q + 3] = v4.w;
                    }
                    float* srow = sb + tl * SROW;
                    for (int j = 0; j < NN; j++) {      // wave-uniform j
                        const float4* pp = pq + j * SS;
                        float num = 0.f, den = 0.f;
#pragma unroll 4
                        for (int s = 0; s < SS; s += 2) {
                            float4 c0 = pp[s];          // broadcast (uniform)
                            float4 c1 = pp[s + 1];
                            float e0 = __builtin_amdgcn_exp2f(fmaf(c0.y, xs[s], c0.x));
                            float e1 = __builtin_amdgcn_exp2f(fmaf(c1.y, xs[s + 1], c1.x));
                            float t0v = 1.0f + e0, t1v = 1.0f + e1;
                            float rD = __builtin_amdgcn_rcpf(t0v * t1v);
                            num = fmaf(fmaf(c0.w, t1v, c1.w * t0v), rD, num);
                            den = fmaf(fmaf(c0.z, t1v, c1.z * t0v), rD, den);
                        }
                        srow[j]      = num;             // stride-39 rows:
                        srow[NN + j] = den;             // 2-way banks = free
                    }
                }
            }
        } else if (c > 0) {              // scan chunk c-1
            const float* sb = sbuf + ((c - 1) & 1) * (CH * SROW);
            float sn = sb[jc], sd = sb[NN + jc];
            int tbase = (c - 1) * CH;
            for (int tl = 0; tl < CH; tl++) {
                float sn_nx = sn, sd_nx = sd;
                if (tl + 1 < CH) {       // prefetch (hidden by 6 unfolds)
                    sn_nx = sb[(tl + 1) * SROW + jc];
                    sd_nx = sb[(tl + 1) * SROW + NN + jc];
                }
                float nbase = glvl + sn, dbase = cgl + sd;
#pragma unroll
                for (int u = 0; u < NUNFOLD; u++) {
                    // uniform pre-neuron sweep: step q covers i = 3q..3q+2;
                    // each lane's own synapse (i = 3q+h) selected by the one
                    // nonzero coefficient among cA/cB/cC.
                    float tv[NU];
#pragma unroll
                    for (int q = 0; q < NU; q++) {
                        float t = fmaf(vS[3 * q], cA[q], sb2[q]);
                        if (3 * q + 1 < NN) t = fmaf(vS[3 * q + 1], cB[q], t);
                        if (3 * q + 2 < NN) t = fmaf(vS[3 * q + 2], cC[q], t);
                        tv[q] = 1.0f + __builtin_amdgcn_exp2f(t);
                    }
                    float pn = 0.f, pd = 0.f;
#pragma unroll
                    for (int p = 0; p < NU / 2; p++) {
                        float t0v = tv[2 * p], t1v = tv[2 * p + 1];
                        float rD  = __builtin_amdgcn_rcpf(t0v * t1v);
                        pn = fmaf(fmaf(Aa[2 * p], t1v, Aa[2 * p + 1] * t0v), rD, pn);
                        pd = fmaf(fmaf(Wm[2 * p], t1v, Wm[2 * p + 1] * t0v), rD, pd);
                    }
                    {   // odd step (q = 6 covers only i = 18)
                        float s1 = __builtin_amdgcn_rcpf(tv[NU - 1]);
                        pn = fmaf(Aa[NU - 1], s1, pn);
                        pd = fmaf(Wm[NU - 1], s1, pd);
                    }
                    // 3-lane DPP reduce: bottom lane of each triple gets sum
                    pn = pn + dpp_shl<0x101>(pn) + dpp_shl<0x102>(pn);
                    pd = pd + dpp_shl<0x101>(pd) + dpp_shl<0x102>(pd);
                    float n = fmaf(cmt, v, nbase);
                    // all lanes update; only leader (bottom) lanes are read
                    v = (n + pn) * __builtin_amdgcn_rcpf(dbase + pd);
                    // VALU-pipe re-broadcast of all 19 v's (replaces bperm)
#pragma unroll
                    for (int jj = 0; jj < NN; jj++)
                        vS[jj] = rdlane(v, (jj / 5) * 16 + (jj % 5) * 3);
                }
                if (lane == 0) obuf[tbase + tl] = fmaf(v, ow0, ob0);
                sn = sn_nx; sd = sd_nx;
            }
        }
        __syncthreads();
    }
}

// ---------------------------------------------------------------------------
// One block per batch element.  Wave 0 scans; waves 1-3 produce; all 4 waves
// run the FC epilogue from LDS.
// ---------------------------------------------------------------------------
__global__ void __launch_bounds__(256, 1)
ltc_fused_kernel(const float* __restrict__ x,
                 const float* __restrict__ iw,  const float* __restrict__ ib,
                 const float* __restrict__ smu, const float* __restrict__ ssig,
                 const float* __restrict__ sw,  const float* __restrict__ serev,
                 const int* __restrict__ smask,
                 const float* __restrict__ mu,  const float* __restrict__ sigma,
                 const float* __restrict__ w,   const float* __restrict__ erev,
                 const int* __restrict__ mask,
                 const float* __restrict__ gleak, const float* __restrict__ vleak,
                 const float* __restrict__ cm,
                 const float* __restrict__ ow,  const float* __restrict__ ob,
                 const float* __restrict__ fcw, const float* __restrict__ fcb,
                 float* __restrict__ out)
{
    __shared__ float4 pq[SS * NN];          // 9.7 KB folded sensory params
    __shared__ float  sbuf[2 * CH * SROW];  // 39.9 KB sens ring (stride 39)
    __shared__ float  obuf[TT];             // 8 KB motor outputs
    __shared__ float  red[4 * NCLASS];      // FC cross-wave reduce

    int tid  = threadIdx.x;
    int b    = blockIdx.x;
    int lane = tid & 63;
    int wid  = tid >> 6;

    // ---- fold sensory params into LDS: pq[j*SS+s] = {P, Qn, W, A} ----
    for (int idx = tid; idx < SS * NN; idx += 256) {
        int j = idx >> 5;
        int s = idx & 31;
        int src = s * NN + j;
        float sg = ssig[src] * LOG2E;
        float P  = sg * smu[src] - sg * ib[s];
        float Qn = -sg * iw[s];
        float wm = sw[src] * (float)smask[src];
        pq[idx] = make_float4(P, Qn, wm, wm * serev[src]);
    }

    // ---- scan-lane mapping: lane = 16*row + pos; pos<15 -> (m = pos/3,
    //      h = pos%3); post-neuron j = 5*row + m; leader = bottom lane ----
    int row = lane >> 4;
    int pos = lane & 15;
    int m   = pos / 3;
    int h   = pos - 3 * m;
    int j   = row * 5 + m;
    bool pad = (pos >= 15) || (j >= NN);
    int jc  = pad ? 0 : j;

    // per-lane params for the uniform sweep: step q handles i = 3q+h.
    // cA/cB/cC multiply vS[3q]/vS[3q+1]/vS[3q+2]; only the h-th is nonzero.
    float cA[NU], cB[NU], cC[NU], sb2[NU], Aa[NU], Wm[NU];
#pragma unroll
    for (int q = 0; q < NU; q++) {
        int i = 3 * q + h;
        bool ok = !pad && (i < NN) && (mask[i * NN + jc] != 0);
        int idx = (ok ? i : 0) * NN + jc;
        float sgl = sigma[idx] * LOG2E;
        float sg2 = ok ? -sgl : 0.f;
        sb2[q] = ok ? sgl * mu[idx] : 0.f;
        float wmm = ok ? w[idx] : 0.f;
        Aa[q] = wmm * erev[idx];
        Wm[q] = wmm;
        cA[q] = (h == 0) ? sg2 : 0.f;
        cB[q] = (h == 1) ? sg2 : 0.f;
        cC[q] = (h == 2) ? sg2 : 0.f;
    }

    float cmt   = cm[jc] * (float)NUNFOLD;
    float gl    = gleak[jc];
    float glvl  = gl * vleak[jc];
    float cgl   = cmt + gl + EPSV;
    float ow0 = ow[0], ob0 = ob[0];

    __syncthreads();   // pq ready before producers start chunk 0

    fused_loop(tid, lane, wid, b, jc, cA, cB, cC, sb2, Aa, Wm,
               cmt, glvl, cgl, ow0, ob0, x, pq, sbuf, obuf);

    // ---- FC epilogue: out[b][c] = sum_t obuf[t]*fcw[c][t] + fcb[c] ----
    float acc[NCLASS];
#pragma unroll
    for (int c = 0; c < NCLASS; c++) acc[c] = 0.f;
    for (int t = tid; t < TT; t += 256) {
        float ov = obuf[t];
#pragma unroll
        for (int c = 0; c < NCLASS; c++)
            acc[c] = fmaf(ov, fcw[c * TT + t], acc[c]);
    }
#pragma unroll
    for (int c = 0; c < NCLASS; c++) {
#pragma unroll
        for (int o2 = 32; o2 > 0; o2 >>= 1)
            acc[c] += __shfl_down(acc[c], o2, 64);
    }
    if (lane == 0) {
#pragma unroll
        for (int c = 0; c < NCLASS; c++) red[wid * NCLASS + c] = acc[c];
    }
    __syncthreads();
    if (tid < NCLASS)
        out[b * NCLASS + tid] = red[tid] + red[NCLASS + tid]
                              + red[2 * NCLASS + tid] + red[3 * NCLASS + tid]
                              + fcb[tid];
}

// ---------------------------------------------------------------------------
extern "C" void kernel_launch(void* const* d_in, const int* in_sizes, int n_in,
                              void* d_out, int out_size, void* d_ws, size_t ws_size,
                              hipStream_t stream)
{
    const float* x     = (const float*)d_in[0];
    const float* iw    = (const float*)d_in[1];
    const float* ib    = (const float*)d_in[2];
    const float* smu   = (const float*)d_in[3];
    const float* ssig  = (const float*)d_in[4];
    const float* sw    = (const float*)d_in[5];
    const float* serev = (const float*)d_in[6];
    const float* mu    = (const float*)d_in[7];
    const float* sigma = (const float*)d_in[8];
    const float* w     = (const float*)d_in[9];
    const float* erev  = (const float*)d_in[10];
    const float* gleak = (const float*)d_in[11];
    const float* vleak = (const float*)d_in[12];
    const float* cm    = (const float*)d_in[13];
    const float* ow    = (const float*)d_in[14];
    const float* ob    = (const float*)d_in[15];
    const float* fcw   = (const float*)d_in[16];
    const float* fcb   = (const float*)d_in[17];
    const int* smask   = (const int*)d_in[18];
    const int* mask    = (const int*)d_in[19];
    float* out = (float*)d_out;

    ltc_fused_kernel<<<BB, 256, 0, stream>>>(x, iw, ib, smu, ssig, sw, serev,
                                             smask, mu, sigma, w, erev, mask,
                                             gleak, vleak, cm, ow, ob,
                                             fcw, fcb, out);
}

// Round 2
// 1673.082 us; speedup vs baseline: 1.4758x; 1.4758x over previous
//
#include <hip/hip_runtime.h>

#define BB 256
#define TT 2048
#define SS 32
#define NN 19
#define NCLASS 10
#define NUNFOLD 6
#define EPSV 1e-8f
#define LOG2E 1.4426950408889634f
#define CH 128                 // timesteps per producer chunk
#define NCH (TT / CH)          // 16 chunks
#define SROW 39                // sens row: 19 num + 19 den + 1 pad (bank-spread)

typedef float v2f __attribute__((ext_vector_type(2)));

// ---------------------------------------------------------------------------
template <int CTRL>
__device__ __forceinline__ float dpp_shl(float x)
{
    return __int_as_float(__builtin_amdgcn_update_dpp(
        0, __float_as_int(x), CTRL, 0xf, 0xf, true));
}

__device__ __forceinline__ float bperm(int addr4, float v)
{
    return __int_as_float(__builtin_amdgcn_ds_bpermute(addr4, __float_as_int(v)));
}

// leader lane of pre-neuron i (rows 2,3 offset +1 => all 19 leaders in
// distinct LDS banks -> conflict-free bpermute broadcast)
__device__ __forceinline__ int lead_lane(int i)
{
    int rw = i / 5;
    return 16 * rw + 3 * (i % 5) + (rw >= 2 ? 1 : 0);
}

// ---------------------------------------------------------------------------
// Fused producer/consumer loop.  Wave 0 = scan chain (compacted bperm
// gather, R8 structure).  Waves 1-3 = sensory producers.  R2 change vs R8:
// packed f32 math (v_pk_fma) in the unfold body + tree-form DPP reduce —
// the unfold is issue-bound on the lone scan wave (R1 post-mortem), so cut
// instruction count without touching the proven gather structure.
// ---------------------------------------------------------------------------
template <int KU>
__device__ __forceinline__ void fused_loop(
    int tid, int lane, int wid, int b, int jc,
    const float (&sg2)[8], const float (&sb2)[8],
    const float (&Aa)[8], const float (&Wm)[8], const int (&src4)[8],
    float cmt, float glvl, float cgl, float ow0, float ob0,
    const float* __restrict__ x,
    const float4* __restrict__ pq,   // LDS: folded sensory params [j*SS+s]
    float* __restrict__ sbuf,        // LDS: [2][CH][SROW]
    float* __restrict__ obuf)        // LDS: [TT] motor outputs
{
    constexpr int NP = KU / 2;

    // packed per-lane constants: sig-arg pairs + {Aa,Wm} channel pairs
    v2f sgv[NP > 0 ? NP : 1], sbv[NP > 0 ? NP : 1], AW[KU];
#pragma unroll
    for (int p = 0; p < NP; p++) {
        sgv[p].x = sg2[2 * p];     sgv[p].y = sg2[2 * p + 1];
        sbv[p].x = sb2[2 * p];     sbv[p].y = sb2[2 * p + 1];
    }
#pragma unroll
    for (int k = 0; k < KU; k++) {
        AW[k].x = Aa[k];           AW[k].y = Wm[k];
    }

    float v = 0.f;
    for (int c = 0; c <= NCH; c++) {
        if (wid != 0) {
            if (c < NCH) {               // produce chunk c
                float* sb = sbuf + (c & 1) * (CH * SROW);
                const float* xb = x + ((long)b * TT + (long)c * CH) * SS;
                for (int tl = tid - 64; tl < CH; tl += 192) {
                    const float4* xr4 = (const float4*)(xb + tl * SS);
                    float xs[SS];
#pragma unroll
                    for (int q = 0; q < SS / 4; q++) {
                        float4 v4 = xr4[q];
                        xs[4 * q + 0] = v4.x; xs[4 * q + 1] = v4.y;
                        xs[4 * q + 2] = v4.z; xs[4 * q + 3] = v4.w;
                    }
                    float* srow = sb + tl * SROW;
                    for (int j = 0; j < NN; j++) {      // wave-uniform j
                        const float4* pp = pq + j * SS;
                        float num = 0.f, den = 0.f;
#pragma unroll 4
                        for (int s = 0; s < SS; s += 2) {
                            float4 c0 = pp[s];          // broadcast (uniform)
                            float4 c1 = pp[s + 1];
                            float e0 = __builtin_amdgcn_exp2f(fmaf(c0.y, xs[s], c0.x));
                            float e1 = __builtin_amdgcn_exp2f(fmaf(c1.y, xs[s + 1], c1.x));
                            float t0v = 1.0f + e0, t1v = 1.0f + e1;
                            float rD = __builtin_amdgcn_rcpf(t0v * t1v);
                            num = fmaf(fmaf(c0.w, t1v, c1.w * t0v), rD, num);
                            den = fmaf(fmaf(c0.z, t1v, c1.z * t0v), rD, den);
                        }
                        srow[j]      = num;             // stride-39 rows:
                        srow[NN + j] = den;             // 2-way banks = free
                    }
                }
            }
        } else if (c > 0) {              // scan chunk c-1
            const float* sb = sbuf + ((c - 1) & 1) * (CH * SROW);
            float sn = sb[jc], sd = sb[NN + jc];
            int tbase = (c - 1) * CH;
            for (int tl = 0; tl < CH; tl++) {
                float sn_nx = sn, sd_nx = sd;
                if (tl + 1 < CH) {       // prefetch (hidden by 6 unfolds)
                    sn_nx = sb[(tl + 1) * SROW + jc];
                    sd_nx = sb[(tl + 1) * SROW + NN + jc];
                }
                float nbase = glvl + sn, dbase = cgl + sd;
#pragma unroll
                for (int u = 0; u < NUNFOLD; u++) {
                    float vi[KU];
#pragma unroll
                    for (int k = 0; k < KU; k++) vi[k] = bperm(src4[k], v);
                    float n = fmaf(cmt, v, nbase);
                    float ev[KU];
#pragma unroll
                    for (int p = 0; p < NP; p++) {       // packed sig args
                        v2f viP;
                        viP.x = vi[2 * p]; viP.y = vi[2 * p + 1];
                        v2f arg = sgv[p] * viP + sbv[p]; // v_pk_fma_f32
                        ev[2 * p]     = __builtin_amdgcn_exp2f(arg.x);
                        ev[2 * p + 1] = __builtin_amdgcn_exp2f(arg.y);
                    }
                    if (KU & 1)
                        ev[KU - 1] = __builtin_amdgcn_exp2f(
                            fmaf(sg2[KU - 1], vi[KU - 1], sb2[KU - 1]));
                    v2f pw = {0.f, 0.f};                 // {pn, pd} packed
#pragma unroll
                    for (int p = 0; p < NP; p++) {
                        float t0v = 1.0f + ev[2 * p];
                        float t1v = 1.0f + ev[2 * p + 1];
                        float rD  = __builtin_amdgcn_rcpf(t0v * t1v);
                        v2f cmb = AW[2 * p] * t1v + AW[2 * p + 1] * t0v;
                        pw = cmb * rD + pw;              // v_pk_fma_f32
                    }
                    if (KU & 1) {
                        float s1 = __builtin_amdgcn_rcpf(1.0f + ev[KU - 1]);
                        pw = AW[KU - 1] * s1 + pw;
                    }
                    // 3-lane DPP reduce, tree form: pn + (shl1 + shl2)
                    float pn = pw.x, pd = pw.y;
                    float an = dpp_shl<0x101>(pn), bn = dpp_shl<0x102>(pn);
                    float ad = dpp_shl<0x101>(pd), bd = dpp_shl<0x102>(pd);
                    pn += an + bn;
                    pd += ad + bd;
                    // all lanes update; only leader lanes are ever read
                    v = (n + pn) * __builtin_amdgcn_rcpf(dbase + pd);
                }
                if (lane == 0) obuf[tbase + tl] = fmaf(v, ow0, ob0);
                sn = sn_nx; sd = sd_nx;
            }
        }
        __syncthreads();
    }
}

// ---------------------------------------------------------------------------
// One block per batch element.  Wave 0 scans; waves 1-3 produce; all 4 waves
// run the FC epilogue from LDS.
// ---------------------------------------------------------------------------
__global__ void __launch_bounds__(256, 1)
ltc_fused_kernel(const float* __restrict__ x,
                 const float* __restrict__ iw,  const float* __restrict__ ib,
                 const float* __restrict__ smu, const float* __restrict__ ssig,
                 const float* __restrict__ sw,  const float* __restrict__ serev,
                 const int* __restrict__ smask,
                 const float* __restrict__ mu,  const float* __restrict__ sigma,
                 const float* __restrict__ w,   const float* __restrict__ erev,
                 const int* __restrict__ mask,
                 const float* __restrict__ gleak, const float* __restrict__ vleak,
                 const float* __restrict__ cm,
                 const float* __restrict__ ow,  const float* __restrict__ ob,
                 const float* __restrict__ fcw, const float* __restrict__ fcb,
                 float* __restrict__ out)
{
    __shared__ float4 pq[SS * NN];          // 9.7 KB folded sensory params
    __shared__ float  sbuf[2 * CH * SROW];  // 39.9 KB sens ring (stride 39)
    __shared__ float  obuf[TT];             // 8 KB motor outputs
    __shared__ float  red[4 * NCLASS];      // FC cross-wave reduce

    int tid  = threadIdx.x;
    int b    = blockIdx.x;
    int lane = tid & 63;
    int wid  = tid >> 6;

    // ---- fold sensory params into LDS: pq[j*SS+s] = {P, Qn, W, A} ----
    for (int idx = tid; idx < SS * NN; idx += 256) {
        int j = idx >> 5;
        int s = idx & 31;
        int src = s * NN + j;
        float sg = ssig[src] * LOG2E;
        float P  = sg * smu[src] - sg * ib[s];
        float Qn = -sg * iw[s];
        float wm = sw[src] * (float)smask[src];
        pq[idx] = make_float4(P, Qn, wm, wm * serev[src]);
    }

    // ---- scan-lane setup (replicated on all waves; depends only on lane,
    //      so every wave derives the identical km for uniform control) ----
    int row  = lane >> 4;
    int pos  = lane & 15;
    int off  = (row >= 2) ? 1 : 0;
    int posr = pos - off;
    int jq   = (posr < 0) ? 5 : posr / 3;
    int rr   = (posr < 0) ? 0 : posr - 3 * jq;
    int j    = row * 5 + jq;
    bool pad = (jq >= 5) || (j >= NN);
    int jc   = pad ? 0 : j;
    int r    = pad ? 0 : rr;

    float sg2[8], sb2[8], Aa[8], Wm[8];
    int src4[8];
    int used = 0;
#pragma unroll
    for (int s = 0; s < 8; s++) {
        int target = 3 * s + r;
        int ii = -1, a = 0;
        for (int i = 0; i < NN; i++) {
            if (mask[i * NN + jc] != 0) {
                if (a == target) ii = i;
                a++;
            }
        }
        bool ok = (ii >= 0) && !pad;
        int iu  = ok ? ii : 0;
        int idx = iu * NN + jc;
        float sgv = sigma[idx];
        float wmm = ok ? w[idx] : 0.f;
        sg2[s] = ok ? (-LOG2E * sgv) : 0.f;
        sb2[s] = ok ? (LOG2E * sgv * mu[idx]) : 0.f;
        Aa[s]  = wmm * erev[idx];
        Wm[s]  = wmm;
        src4[s] = lead_lane(iu) << 2;
        if (ok) used = s + 1;
    }
    int km = used;
#pragma unroll
    for (int o = 1; o < 64; o <<= 1) {
        int other = __shfl_xor(km, o, 64);
        km = km > other ? km : other;
    }

    float cmt   = cm[jc] * (float)NUNFOLD;
    float gl    = gleak[jc];
    float glvl  = gl * vleak[jc];
    float cgl   = cmt + gl + EPSV;
    float ow0 = ow[0], ob0 = ob[0];

    __syncthreads();   // pq ready before producers start chunk 0

    if (km <= 3)
        fused_loop<3>(tid, lane, wid, b, jc, sg2, sb2, Aa, Wm, src4,
                      cmt, glvl, cgl, ow0, ob0, x, pq, sbuf, obuf);
    else if (km == 4)
        fused_loop<4>(tid, lane, wid, b, jc, sg2, sb2, Aa, Wm, src4,
                      cmt, glvl, cgl, ow0, ob0, x, pq, sbuf, obuf);
    else if (km == 5)
        fused_loop<5>(tid, lane, wid, b, jc, sg2, sb2, Aa, Wm, src4,
                      cmt, glvl, cgl, ow0, ob0, x, pq, sbuf, obuf);
    else if (km == 6)
        fused_loop<6>(tid, lane, wid, b, jc, sg2, sb2, Aa, Wm, src4,
                      cmt, glvl, cgl, ow0, ob0, x, pq, sbuf, obuf);
    else
        fused_loop<7>(tid, lane, wid, b, jc, sg2, sb2, Aa, Wm, src4,
                      cmt, glvl, cgl, ow0, ob0, x, pq, sbuf, obuf);

    // ---- FC epilogue: out[b][c] = sum_t obuf[t]*fcw[c][t] + fcb[c] ----
    float acc[NCLASS];
#pragma unroll
    for (int c = 0; c < NCLASS; c++) acc[c] = 0.f;
    for (int t = tid; t < TT; t += 256) {
        float ov = obuf[t];
#pragma unroll
        for (int c = 0; c < NCLASS; c++)
            acc[c] = fmaf(ov, fcw[c * TT + t], acc[c]);
    }
#pragma unroll
    for (int c = 0; c < NCLASS; c++) {
#pragma unroll
        for (int o2 = 32; o2 > 0; o2 >>= 1)
            acc[c] += __shfl_down(acc[c], o2, 64);
    }
    if (lane == 0) {
#pragma unroll
        for (int c = 0; c < NCLASS; c++) red[wid * NCLASS + c] = acc[c];
    }
    __syncthreads();
    if (tid < NCLASS)
        out[b * NCLASS + tid] = red[tid] + red[NCLASS + tid]
                              + red[2 * NCLASS + tid] + red[3 * NCLASS + tid]
                              + fcb[tid];
}

// ---------------------------------------------------------------------------
extern "C" void kernel_launch(void* const* d_in, const int* in_sizes, int n_in,
                              void* d_out, int out_size, void* d_ws, size_t ws_size,
                              hipStream_t stream)
{
    const float* x     = (const float*)d_in[0];
    const float* iw    = (const float*)d_in[1];
    const float* ib    = (const float*)d_in[2];
    const float* smu   = (const float*)d_in[3];
    const float* ssig  = (const float*)d_in[4];
    const float* sw    = (const float*)d_in[5];
    const float* serev = (const float*)d_in[6];
    const float* mu    = (const float*)d_in[7];
    const float* sigma = (const float*)d_in[8];
    const float* w     = (const float*)d_in[9];
    const float* erev  = (const float*)d_in[10];
    const float* gleak = (const float*)d_in[11];
    const float* vleak = (const float*)d_in[12];
    const float* cm    = (const float*)d_in[13];
    const float* ow    = (const float*)d_in[14];
    const float* ob    = (const float*)d_in[15];
    const float* fcw   = (const float*)d_in[16];
    const float* fcb   = (const float*)d_in[17];
    const int* smask   = (const int*)d_in[18];
    const int* mask    = (const int*)d_in[19];
    float* out = (float*)d_out;

    ltc_fused_kernel<<<BB, 256, 0, stream>>>(x, iw, ib, smu, ssig, sw, serev,
                                             smask, mu, sigma, w, erev, mask,
                                             gleak, vleak, cm, ow, ob,
                                             fcw, fcb, out);
}